// Round 3
// baseline (1013.535 us; speedup 1.0000x reference)
//
#include <hip/hip_runtime.h>
#include <hip/hip_bf16.h>

typedef __bf16 bf16;
typedef __bf16 bf16x8 __attribute__((ext_vector_type(8)));
typedef float f32x4 __attribute__((ext_vector_type(4)));

#define QSCALE 0.18033688011112042f  /* (1/8) * log2(e) : folds softmax scale into Wq */

// raw v_exp_f32 (exp2). Inputs here are |x| <~ 2.5 so no edge-case handling needed.
#define EXP2(x) __builtin_amdgcn_exp2f(x)

// ---- async global->LDS (16B per lane, wave-uniform LDS base + lane*16) ----
__device__ __forceinline__ void load_lds16(const void* gp, void* lp) {
  __builtin_amdgcn_global_load_lds((const __attribute__((address_space(1))) void*)gp,
                                   (__attribute__((address_space(3))) void*)lp, 16, 0, 0);
}

// ---------------------------------------------------------------------------
// Kernel T: x [B,C,N] fp32 -> t [B,N,C] bf16   (B=32, C=640, N=1024)
// ---------------------------------------------------------------------------
__global__ __launch_bounds__(256) void k_transpose(const float* __restrict__ x,
                                                   bf16* __restrict__ t) {
  __shared__ float tile[64][65];
  const int b = blockIdx.z, c0 = blockIdx.y * 64, n0 = blockIdx.x * 64;
  const int tid = threadIdx.x, lx = tid & 63, ly = tid >> 6;
  const float* xp = x + ((size_t)b * 640 + c0) * 1024 + n0;
#pragma unroll
  for (int i = 0; i < 16; ++i) {
    int c = i * 4 + ly;
    tile[c][lx] = xp[(size_t)c * 1024 + lx];
  }
  __syncthreads();
  bf16* tp = t + ((size_t)b * 1024 + n0) * 640 + c0;
#pragma unroll
  for (int i = 0; i < 16; ++i) {
    int n = i * 4 + ly;
    tp[(size_t)n * 640 + lx] = (bf16)tile[lx][n];
  }
}

// ---------------------------------------------------------------------------
// Kernel Wc: cast one weight matrix [1024,640] fp32 -> bf16 (optionally scaled)
// ---------------------------------------------------------------------------
__global__ __launch_bounds__(256) void k_castw(const float* __restrict__ w,
                                               bf16* __restrict__ dst, float s) {
  int i = blockIdx.x * 256 + threadIdx.x;
  if (i < 655360) dst[i] = (bf16)(w[i] * s);
}

// ---------------------------------------------------------------------------
// Kernel P: C[32768 x 3072] = A[32768 x 640] * B[3072 x 640]^T  (bf16 in, bf16 out)
// 128x128 tile, BK=64, 4 waves (2x2), 16x16x32 MFMA, global_load_lds + XOR swizzle.
// Epilogue scatters into q/k/v [BH=512][N=1024][64] bf16.
// ---------------------------------------------------------------------------
__global__ __launch_bounds__(256) void k_gemm_qkv(const bf16* __restrict__ A,
                                                  const bf16* __restrict__ Bw,
                                                  bf16* __restrict__ qkv) {
  __shared__ __align__(16) bf16 As[128 * 64];
  __shared__ __align__(16) bf16 Bs[128 * 64];
  const int tid = threadIdx.x;
  const int lane = tid & 63;
  const int w = tid >> 6;
  const int wm = w & 1, wn = w >> 1;
  const int g = lane >> 4, ln = lane & 15;
  const int m0 = blockIdx.x * 128;
  const int n0 = blockIdx.y * 128;

  f32x4 acc[4][4];
#pragma unroll
  for (int i = 0; i < 4; ++i)
#pragma unroll
    for (int j = 0; j < 4; ++j)
#pragma unroll
      for (int r = 0; r < 4; ++r) acc[i][j][r] = 0.f;

  for (int k0 = 0; k0 < 640; k0 += 64) {
    // stage A and B tiles: 1024 16B-chunks each; chunk c holds global (m=c>>3, kq=(c&7)^(m&7))
#pragma unroll
    for (int it = 0; it < 4; ++it) {
      int c = it * 256 + w * 64 + lane;
      int m = c >> 3;
      int kq = (c & 7) ^ (m & 7);
      load_lds16(A + (size_t)(m0 + m) * 640 + (k0 + kq * 8), As + (size_t)(it * 256 + w * 64) * 8);
      load_lds16(Bw + (size_t)(n0 + m) * 640 + (k0 + kq * 8), Bs + (size_t)(it * 256 + w * 64) * 8);
    }
    __syncthreads();
#pragma unroll
    for (int kk = 0; kk < 2; ++kk) {
      bf16x8 af[4], bfr[4];
#pragma unroll
      for (int mi = 0; mi < 4; ++mi) {
        int m = wm * 64 + mi * 16 + ln;
        int cc = m * 8 + ((kk * 4 + g) ^ (m & 7));
        af[mi] = *(const bf16x8*)(As + cc * 8);
      }
#pragma unroll
      for (int ni = 0; ni < 4; ++ni) {
        int n = wn * 64 + ni * 16 + ln;
        int cc = n * 8 + ((kk * 4 + g) ^ (n & 7));
        bfr[ni] = *(const bf16x8*)(Bs + cc * 8);
      }
#pragma unroll
      for (int mi = 0; mi < 4; ++mi)
#pragma unroll
        for (int ni = 0; ni < 4; ++ni)
          acc[mi][ni] = __builtin_amdgcn_mfma_f32_16x16x32_bf16(af[mi], bfr[ni], acc[mi][ni], 0, 0, 0);
    }
    __syncthreads();
  }

  // epilogue: D layout col=lane&15, row=(lane>>4)*4+r  -> scatter to q/k/v [bh][n][d]
#pragma unroll
  for (int mi = 0; mi < 4; ++mi)
#pragma unroll
    for (int ni = 0; ni < 4; ++ni)
#pragma unroll
      for (int r = 0; r < 4; ++r) {
        int row = m0 + wm * 64 + mi * 16 + g * 4 + r;   // (b,n)
        int col = n0 + wn * 64 + ni * 16 + ln;          // (which,h,d)
        int bb = row >> 10, n = row & 1023;
        int which = col >> 10, h = (col >> 6) & 15, d = col & 63;
        qkv[(size_t)which * 33554432 +
            ((((size_t)bb * 16 + h) * 1024 + n) * 64 + d)] = (bf16)acc[mi][ni][r];
      }
}

// ---------------------------------------------------------------------------
// Kernel A: fused two-pass attention column-weights.
// grid 2048 1-D; decode so the 4 i-tiles of one bh land on the SAME XCD
// (idx % 8 equal) -> K re-reads hit that XCD's L2 instead of HBM.
// Per jt, K fragments are register double-buffered: prefetch jt+1 during
// jt's MFMA+exp compute to hide L2 latency.
// Pass 1: l_i = sum_j exp2(s_ij)  (q pre-scaled by scale*log2e)
// Pass 2: w_j += sum_i exp2(s_ij) / l_i   via atomicAdd.
// ---------------------------------------------------------------------------
#define LOADK(buf, jt)                                                        \
  do {                                                                        \
    const bf16* kp_ = kb + (size_t)(jt) * 4096 + ln * 64 + g * 8;             \
    _Pragma("unroll") for (int ni_ = 0; ni_ < 4; ++ni_) {                     \
      buf[ni_ * 2 + 0] = *(const bf16x8*)(kp_ + ni_ * 1024);                  \
      buf[ni_ * 2 + 1] = *(const bf16x8*)(kp_ + ni_ * 1024 + 32);             \
    }                                                                         \
  } while (0)

__global__ __launch_bounds__(256) void k_attn(const bf16* __restrict__ q,
                                              const bf16* __restrict__ kmat,
                                              float* __restrict__ wsum) {
  const int idx = blockIdx.x;
  const int xcd = idx & 7;
  const int y = idx >> 3;
  const int it = y & 3;
  const int bh = xcd + ((y >> 2) << 3);   // 4 i-tiles of bh share idx%8
  const int tid = threadIdx.x;
  const int lane = tid & 63;
  const int w = tid >> 6;
  const int g = lane >> 4, ln = lane & 15;
  const bf16* qb = q + (size_t)bh * 65536;
  const bf16* kb = kmat + (size_t)bh * 65536;
  const int i0 = it * 256 + w * 64;

  const f32x4 zf = {0.f, 0.f, 0.f, 0.f};

  // Q fragments: A-layout m=lane&15, k=(lane>>4)*8+j ; held in regs for both passes
  bf16x8 qf[4][2];
#pragma unroll
  for (int mi = 0; mi < 4; ++mi)
#pragma unroll
    for (int kc = 0; kc < 2; ++kc)
      qf[mi][kc] = *(const bf16x8*)(qb + (size_t)(i0 + mi * 16 + ln) * 64 + kc * 32 + g * 8);

  float rs[4][4];
#pragma unroll
  for (int mi = 0; mi < 4; ++mi)
#pragma unroll
    for (int r = 0; r < 4; ++r) rs[mi][r] = 0.f;

  bf16x8 kbuf[2][8];

  // ---- pass 1: row sums ----
  LOADK(kbuf[0], 0);
  for (int jt = 0; jt < 16; ++jt) {
    if (jt < 15) LOADK(kbuf[(jt + 1) & 1], jt + 1);
    const bf16x8* kf = kbuf[jt & 1];
#pragma unroll
    for (int mi = 0; mi < 4; ++mi)
#pragma unroll
      for (int ni = 0; ni < 4; ++ni) {
        f32x4 s = __builtin_amdgcn_mfma_f32_16x16x32_bf16(qf[mi][0], kf[ni * 2], zf, 0, 0, 0);
        s = __builtin_amdgcn_mfma_f32_16x16x32_bf16(qf[mi][1], kf[ni * 2 + 1], s, 0, 0, 0);
#pragma unroll
        for (int r = 0; r < 4; ++r) rs[mi][r] += EXP2(s[r]);
      }
  }
  // reduce row sums across the 16 lanes sharing g (cols live in lane&15)
  float rinv[4][4];
#pragma unroll
  for (int mi = 0; mi < 4; ++mi)
#pragma unroll
    for (int r = 0; r < 4; ++r) {
      float v = rs[mi][r];
      v += __shfl_xor(v, 1);
      v += __shfl_xor(v, 2);
      v += __shfl_xor(v, 4);
      v += __shfl_xor(v, 8);
      rinv[mi][r] = 1.0f / v;
    }

  // ---- pass 2: column sums scaled by 1/l_i ----
  LOADK(kbuf[0], 0);
  for (int jt = 0; jt < 16; ++jt) {
    if (jt < 15) LOADK(kbuf[(jt + 1) & 1], jt + 1);
    const bf16x8* kf = kbuf[jt & 1];
    float cs[4] = {0.f, 0.f, 0.f, 0.f};
#pragma unroll
    for (int mi = 0; mi < 4; ++mi)
#pragma unroll
      for (int ni = 0; ni < 4; ++ni) {
        f32x4 s = __builtin_amdgcn_mfma_f32_16x16x32_bf16(qf[mi][0], kf[ni * 2], zf, 0, 0, 0);
        s = __builtin_amdgcn_mfma_f32_16x16x32_bf16(qf[mi][1], kf[ni * 2 + 1], s, 0, 0, 0);
#pragma unroll
        for (int r = 0; r < 4; ++r) cs[ni] += EXP2(s[r]) * rinv[mi][r];
      }
#pragma unroll
    for (int ni = 0; ni < 4; ++ni) {
      float v = cs[ni];
      v += __shfl_xor(v, 16);
      v += __shfl_xor(v, 32);
      if (g == 0) atomicAdd(wsum + (size_t)bh * 1024 + jt * 64 + ni * 16 + ln, v);
    }
  }
}

// ---------------------------------------------------------------------------
// Kernel F: out[bh][d] = LN_d( (1/N) * sum_j w[bh][j] * V[bh][j][d] )
// ---------------------------------------------------------------------------
__global__ __launch_bounds__(256) void k_final(const float* __restrict__ wsum,
                                               const bf16* __restrict__ v,
                                               const float* __restrict__ gamma,
                                               const float* __restrict__ beta,
                                               float* __restrict__ out) {
  const int bh = blockIdx.x;
  const int tid = threadIdx.x;
  const int d = tid & 63, part = tid >> 6;
  const bf16* vb = v + (size_t)bh * 65536;
  const float* wb = wsum + (size_t)bh * 1024;
  float acc = 0.f;
  for (int j = part * 256; j < part * 256 + 256; ++j)
    acc += wb[j] * (float)vb[(size_t)j * 64 + d];
  __shared__ float red[4][64];
  red[part][d] = acc;
  __syncthreads();
  if (tid < 64) {
    float y = (red[0][d] + red[1][d] + red[2][d] + red[3][d]) * (1.0f / 1024.0f);
    float s1 = y;
#pragma unroll
    for (int off = 1; off < 64; off <<= 1) s1 += __shfl_xor(s1, off);
    float mu = s1 * (1.0f / 64.0f);
    float dy = y - mu;
    float s2 = dy * dy;
#pragma unroll
    for (int off = 1; off < 64; off <<= 1) s2 += __shfl_xor(s2, off);
    float rstd = rsqrtf(s2 * (1.0f / 64.0f) + 1e-5f);
    out[(size_t)bh * 64 + d] = dy * rstd * gamma[d] + beta[d];
  }
}

// ---------------------------------------------------------------------------
extern "C" void kernel_launch(void* const* d_in, const int* in_sizes, int n_in,
                              void* d_out, int out_size, void* d_ws, size_t ws_size,
                              hipStream_t stream) {
  const float* x     = (const float*)d_in[0];
  const float* Wq    = (const float*)d_in[1];
  const float* Wk    = (const float*)d_in[2];
  const float* Wv    = (const float*)d_in[3];
  const float* gamma = (const float*)d_in[4];
  const float* beta  = (const float*)d_in[5];
  float* out = (float*)d_out;

  char* ws = (char*)d_ws;
  bf16*  tbf  = (bf16*)ws;                    // 32768*640*2      = 41,943,040 B
  bf16*  wbf  = (bf16*)(ws + 41943040);       // 3072*640*2       =  3,932,160 B
  bf16*  qkv  = (bf16*)(ws + 45875200);       // 3*512*1024*64*2  = 201,326,592 B
  float* wsum = (float*)(ws + 247201792);     // 512*1024*4       =  2,097,152 B

  hipMemsetAsync(wsum, 0, (size_t)512 * 1024 * sizeof(float), stream);
  k_transpose<<<dim3(16, 10, 32), 256, 0, stream>>>(x, tbf);
  k_castw<<<2560, 256, 0, stream>>>(Wq, wbf, QSCALE);
  k_castw<<<2560, 256, 0, stream>>>(Wk, wbf + 655360, 1.0f);
  k_castw<<<2560, 256, 0, stream>>>(Wv, wbf + 1310720, 1.0f);
  k_gemm_qkv<<<dim3(256, 24), 256, 0, stream>>>(tbf, wbf, qkv);
  k_attn<<<2048, 256, 0, stream>>>(qkv, qkv + 33554432, wsum);
  k_final<<<512, 256, 0, stream>>>(wsum, qkv + 67108864, gamma, beta, out);
}

// Round 4
// 618.371 us; speedup vs baseline: 1.6390x; 1.6390x over previous
//
#include <hip/hip_runtime.h>
#include <hip/hip_bf16.h>

typedef __bf16 bf16;
typedef __bf16 bf16x8 __attribute__((ext_vector_type(8)));
typedef float f32x4 __attribute__((ext_vector_type(4)));

#define QSCALE 0.18033688011112042f  /* (1/8) * log2(e) : folds softmax scale into Wq */

// raw v_exp_f32 (exp2). Inputs here are |x| <~ 2.5 so no edge-case handling needed.
#define EXP2(x) __builtin_amdgcn_exp2f(x)

// ---- async global->LDS (16B per lane, wave-uniform LDS base + lane*16) ----
__device__ __forceinline__ void load_lds16(const void* gp, void* lp) {
  __builtin_amdgcn_global_load_lds((const __attribute__((address_space(1))) void*)gp,
                                   (__attribute__((address_space(3))) void*)lp, 16, 0, 0);
}

// ---------------------------------------------------------------------------
// Kernel T: x [B,C,N] fp32 -> t [B,N,C] bf16   (B=32, C=640, N=1024)
// ---------------------------------------------------------------------------
__global__ __launch_bounds__(256) void k_transpose(const float* __restrict__ x,
                                                   bf16* __restrict__ t) {
  __shared__ float tile[64][65];
  const int b = blockIdx.z, c0 = blockIdx.y * 64, n0 = blockIdx.x * 64;
  const int tid = threadIdx.x, lx = tid & 63, ly = tid >> 6;
  const float* xp = x + ((size_t)b * 640 + c0) * 1024 + n0;
#pragma unroll
  for (int i = 0; i < 16; ++i) {
    int c = i * 4 + ly;
    tile[c][lx] = xp[(size_t)c * 1024 + lx];
  }
  __syncthreads();
  bf16* tp = t + ((size_t)b * 1024 + n0) * 640 + c0;
#pragma unroll
  for (int i = 0; i < 16; ++i) {
    int n = i * 4 + ly;
    tp[(size_t)n * 640 + lx] = (bf16)tile[lx][n];
  }
}

// ---------------------------------------------------------------------------
// Kernel Wc: cast one weight matrix [1024,640] fp32 -> bf16 (optionally scaled)
// ---------------------------------------------------------------------------
__global__ __launch_bounds__(256) void k_castw(const float* __restrict__ w,
                                               bf16* __restrict__ dst, float s) {
  int i = blockIdx.x * 256 + threadIdx.x;
  if (i < 655360) dst[i] = (bf16)(w[i] * s);
}

// ---------------------------------------------------------------------------
// Kernel P: C[32768 x 3072] = A[32768 x 640] * B[3072 x 640]^T  (bf16 in, bf16 out)
// 128x128 tile, BK=64, 4 waves (2x2), 16x16x32 MFMA, global_load_lds + XOR swizzle.
// Epilogue scatters into q/k/v [BH=512][N=1024][64] bf16.
// ---------------------------------------------------------------------------
__global__ __launch_bounds__(256) void k_gemm_qkv(const bf16* __restrict__ A,
                                                  const bf16* __restrict__ Bw,
                                                  bf16* __restrict__ qkv) {
  __shared__ __align__(16) bf16 As[128 * 64];
  __shared__ __align__(16) bf16 Bs[128 * 64];
  const int tid = threadIdx.x;
  const int lane = tid & 63;
  const int w = tid >> 6;
  const int wm = w & 1, wn = w >> 1;
  const int g = lane >> 4, ln = lane & 15;
  const int m0 = blockIdx.x * 128;
  const int n0 = blockIdx.y * 128;

  f32x4 acc[4][4];
#pragma unroll
  for (int i = 0; i < 4; ++i)
#pragma unroll
    for (int j = 0; j < 4; ++j)
#pragma unroll
      for (int r = 0; r < 4; ++r) acc[i][j][r] = 0.f;

  for (int k0 = 0; k0 < 640; k0 += 64) {
    // stage A and B tiles: 1024 16B-chunks each; chunk c holds global (m=c>>3, kq=(c&7)^(m&7))
#pragma unroll
    for (int it = 0; it < 4; ++it) {
      int c = it * 256 + w * 64 + lane;
      int m = c >> 3;
      int kq = (c & 7) ^ (m & 7);
      load_lds16(A + (size_t)(m0 + m) * 640 + (k0 + kq * 8), As + (size_t)(it * 256 + w * 64) * 8);
      load_lds16(Bw + (size_t)(n0 + m) * 640 + (k0 + kq * 8), Bs + (size_t)(it * 256 + w * 64) * 8);
    }
    __syncthreads();
#pragma unroll
    for (int kk = 0; kk < 2; ++kk) {
      bf16x8 af[4], bfr[4];
#pragma unroll
      for (int mi = 0; mi < 4; ++mi) {
        int m = wm * 64 + mi * 16 + ln;
        int cc = m * 8 + ((kk * 4 + g) ^ (m & 7));
        af[mi] = *(const bf16x8*)(As + cc * 8);
      }
#pragma unroll
      for (int ni = 0; ni < 4; ++ni) {
        int n = wn * 64 + ni * 16 + ln;
        int cc = n * 8 + ((kk * 4 + g) ^ (n & 7));
        bfr[ni] = *(const bf16x8*)(Bs + cc * 8);
      }
#pragma unroll
      for (int mi = 0; mi < 4; ++mi)
#pragma unroll
        for (int ni = 0; ni < 4; ++ni)
          acc[mi][ni] = __builtin_amdgcn_mfma_f32_16x16x32_bf16(af[mi], bfr[ni], acc[mi][ni], 0, 0, 0);
    }
    __syncthreads();
  }

  // epilogue: D layout col=lane&15, row=(lane>>4)*4+r  -> scatter to q/k/v [bh][n][d]
#pragma unroll
  for (int mi = 0; mi < 4; ++mi)
#pragma unroll
    for (int ni = 0; ni < 4; ++ni)
#pragma unroll
      for (int r = 0; r < 4; ++r) {
        int row = m0 + wm * 64 + mi * 16 + g * 4 + r;   // (b,n)
        int col = n0 + wn * 64 + ni * 16 + ln;          // (which,h,d)
        int bb = row >> 10, n = row & 1023;
        int which = col >> 10, h = (col >> 6) & 15, d = col & 63;
        qkv[(size_t)which * 33554432 +
            ((((size_t)bb * 16 + h) * 1024 + n) * 64 + d)] = (bf16)acc[mi][ni][r];
      }
}

// ---------------------------------------------------------------------------
// Kernel A: fused two-pass attention column-weights.
// grid 2048 1-D; decode so the 4 i-tiles of one bh land on the SAME XCD
// (idx % 8 equal) -> K re-reads hit that XCD's L2 instead of HBM.
// K fragments register double-buffered via TWO NAMED arrays + jt loop
// unrolled x2 (constant indices only -> stays in VGPRs; runtime-indexed
// local arrays spill to scratch: R3 post-mortem, 2 GB scratch traffic).
// Pass 1: l_i = sum_j exp2(s_ij)  (q pre-scaled by scale*log2e)
// Pass 2: w_j += sum_i exp2(s_ij) / l_i   via atomicAdd.
// ---------------------------------------------------------------------------
#define LOADK(buf, jt)                                                        \
  do {                                                                        \
    const bf16* kp_ = kb + (size_t)(jt) * 4096 + ln * 64 + g * 8;             \
    _Pragma("unroll") for (int ni_ = 0; ni_ < 4; ++ni_) {                     \
      buf[ni_ * 2 + 0] = *(const bf16x8*)(kp_ + ni_ * 1024);                  \
      buf[ni_ * 2 + 1] = *(const bf16x8*)(kp_ + ni_ * 1024 + 32);             \
    }                                                                         \
  } while (0)

#define PASS1_COMPUTE(kf)                                                     \
  do {                                                                        \
    _Pragma("unroll") for (int mi = 0; mi < 4; ++mi)                          \
      _Pragma("unroll") for (int ni = 0; ni < 4; ++ni) {                      \
        f32x4 s = __builtin_amdgcn_mfma_f32_16x16x32_bf16(qf[mi][0], kf[ni * 2], zf, 0, 0, 0); \
        s = __builtin_amdgcn_mfma_f32_16x16x32_bf16(qf[mi][1], kf[ni * 2 + 1], s, 0, 0, 0);    \
        _Pragma("unroll") for (int r = 0; r < 4; ++r) rs[mi][r] += EXP2(s[r]);\
      }                                                                       \
  } while (0)

#define PASS2_COMPUTE(kf, jt)                                                 \
  do {                                                                        \
    float cs[4] = {0.f, 0.f, 0.f, 0.f};                                       \
    _Pragma("unroll") for (int mi = 0; mi < 4; ++mi)                          \
      _Pragma("unroll") for (int ni = 0; ni < 4; ++ni) {                      \
        f32x4 s = __builtin_amdgcn_mfma_f32_16x16x32_bf16(qf[mi][0], kf[ni * 2], zf, 0, 0, 0); \
        s = __builtin_amdgcn_mfma_f32_16x16x32_bf16(qf[mi][1], kf[ni * 2 + 1], s, 0, 0, 0);    \
        _Pragma("unroll") for (int r = 0; r < 4; ++r) cs[ni] += EXP2(s[r]) * rinv[mi][r];      \
      }                                                                       \
    _Pragma("unroll") for (int ni = 0; ni < 4; ++ni) {                        \
      float v = cs[ni];                                                       \
      v += __shfl_xor(v, 16);                                                 \
      v += __shfl_xor(v, 32);                                                 \
      if (g == 0) atomicAdd(wsum + (size_t)bh * 1024 + (jt) * 64 + ni * 16 + ln, v); \
    }                                                                         \
  } while (0)

__global__ __launch_bounds__(256) void k_attn(const bf16* __restrict__ q,
                                              const bf16* __restrict__ kmat,
                                              float* __restrict__ wsum) {
  const int idx = blockIdx.x;
  const int xcd = idx & 7;
  const int y = idx >> 3;
  const int it = y & 3;
  const int bh = xcd + ((y >> 2) << 3);   // 4 i-tiles of bh share idx%8
  const int tid = threadIdx.x;
  const int lane = tid & 63;
  const int w = tid >> 6;
  const int g = lane >> 4, ln = lane & 15;
  const bf16* qb = q + (size_t)bh * 65536;
  const bf16* kb = kmat + (size_t)bh * 65536;
  const int i0 = it * 256 + w * 64;

  const f32x4 zf = {0.f, 0.f, 0.f, 0.f};

  // Q fragments: A-layout m=lane&15, k=(lane>>4)*8+j ; held in regs for both passes
  bf16x8 qf[4][2];
#pragma unroll
  for (int mi = 0; mi < 4; ++mi)
#pragma unroll
    for (int kc = 0; kc < 2; ++kc)
      qf[mi][kc] = *(const bf16x8*)(qb + (size_t)(i0 + mi * 16 + ln) * 64 + kc * 32 + g * 8);

  float rs[4][4];
#pragma unroll
  for (int mi = 0; mi < 4; ++mi)
#pragma unroll
    for (int r = 0; r < 4; ++r) rs[mi][r] = 0.f;

  bf16x8 ka[8], kb2[8];

  // ---- pass 1: row sums (jt unrolled x2, named double buffers) ----
  LOADK(ka, 0);
  for (int jt = 0; jt < 16; jt += 2) {
    LOADK(kb2, jt + 1);
    PASS1_COMPUTE(ka);
    if (jt + 2 < 16) LOADK(ka, jt + 2);
    PASS1_COMPUTE(kb2);
  }
  // reduce row sums across the 16 lanes sharing g (cols live in lane&15)
  float rinv[4][4];
#pragma unroll
  for (int mi = 0; mi < 4; ++mi)
#pragma unroll
    for (int r = 0; r < 4; ++r) {
      float v = rs[mi][r];
      v += __shfl_xor(v, 1);
      v += __shfl_xor(v, 2);
      v += __shfl_xor(v, 4);
      v += __shfl_xor(v, 8);
      rinv[mi][r] = 1.0f / v;
    }

  // ---- pass 2: column sums scaled by 1/l_i ----
  LOADK(ka, 0);
  for (int jt = 0; jt < 16; jt += 2) {
    LOADK(kb2, jt + 1);
    PASS2_COMPUTE(ka, jt);
    if (jt + 2 < 16) LOADK(ka, jt + 2);
    PASS2_COMPUTE(kb2, jt + 1);
  }
}

// ---------------------------------------------------------------------------
// Kernel F: out[bh][d] = LN_d( (1/N) * sum_j w[bh][j] * V[bh][j][d] )
// ---------------------------------------------------------------------------
__global__ __launch_bounds__(256) void k_final(const float* __restrict__ wsum,
                                               const bf16* __restrict__ v,
                                               const float* __restrict__ gamma,
                                               const float* __restrict__ beta,
                                               float* __restrict__ out) {
  const int bh = blockIdx.x;
  const int tid = threadIdx.x;
  const int d = tid & 63, part = tid >> 6;
  const bf16* vb = v + (size_t)bh * 65536;
  const float* wb = wsum + (size_t)bh * 1024;
  float acc = 0.f;
  for (int j = part * 256; j < part * 256 + 256; ++j)
    acc += wb[j] * (float)vb[(size_t)j * 64 + d];
  __shared__ float red[4][64];
  red[part][d] = acc;
  __syncthreads();
  if (tid < 64) {
    float y = (red[0][d] + red[1][d] + red[2][d] + red[3][d]) * (1.0f / 1024.0f);
    float s1 = y;
#pragma unroll
    for (int off = 1; off < 64; off <<= 1) s1 += __shfl_xor(s1, off);
    float mu = s1 * (1.0f / 64.0f);
    float dy = y - mu;
    float s2 = dy * dy;
#pragma unroll
    for (int off = 1; off < 64; off <<= 1) s2 += __shfl_xor(s2, off);
    float rstd = rsqrtf(s2 * (1.0f / 64.0f) + 1e-5f);
    out[(size_t)bh * 64 + d] = dy * rstd * gamma[d] + beta[d];
  }
}

// ---------------------------------------------------------------------------
extern "C" void kernel_launch(void* const* d_in, const int* in_sizes, int n_in,
                              void* d_out, int out_size, void* d_ws, size_t ws_size,
                              hipStream_t stream) {
  const float* x     = (const float*)d_in[0];
  const float* Wq    = (const float*)d_in[1];
  const float* Wk    = (const float*)d_in[2];
  const float* Wv    = (const float*)d_in[3];
  const float* gamma = (const float*)d_in[4];
  const float* beta  = (const float*)d_in[5];
  float* out = (float*)d_out;

  char* ws = (char*)d_ws;
  bf16*  tbf  = (bf16*)ws;                    // 32768*640*2      = 41,943,040 B
  bf16*  wbf  = (bf16*)(ws + 41943040);       // 3072*640*2       =  3,932,160 B
  bf16*  qkv  = (bf16*)(ws + 45875200);       // 3*512*1024*64*2  = 201,326,592 B
  float* wsum = (float*)(ws + 247201792);     // 512*1024*4       =  2,097,152 B

  hipMemsetAsync(wsum, 0, (size_t)512 * 1024 * sizeof(float), stream);
  k_transpose<<<dim3(16, 10, 32), 256, 0, stream>>>(x, tbf);
  k_castw<<<2560, 256, 0, stream>>>(Wq, wbf, QSCALE);
  k_castw<<<2560, 256, 0, stream>>>(Wk, wbf + 655360, 1.0f);
  k_castw<<<2560, 256, 0, stream>>>(Wv, wbf + 1310720, 1.0f);
  k_gemm_qkv<<<dim3(256, 24), 256, 0, stream>>>(tbf, wbf, qkv);
  k_attn<<<2048, 256, 0, stream>>>(qkv, qkv + 33554432, wsum);
  k_final<<<512, 256, 0, stream>>>(wsum, qkv + 67108864, gamma, beta, out);
}

// Round 5
// 566.412 us; speedup vs baseline: 1.7894x; 1.0917x over previous
//
#include <hip/hip_runtime.h>
#include <hip/hip_bf16.h>

typedef __bf16 bf16;
typedef __bf16 bf16x8 __attribute__((ext_vector_type(8)));
typedef float f32x4 __attribute__((ext_vector_type(4)));

#define QSCALE 0.18033688011112042f  /* (1/8) * log2(e) : folds softmax scale into Wq */

// raw v_exp_f32 (exp2). Inputs here are |x| <~ 2.5 so no edge-case handling needed.
#define EXP2(x) __builtin_amdgcn_exp2f(x)

// ---- async global->LDS (16B per lane, wave-uniform LDS base + lane*16) ----
__device__ __forceinline__ void load_lds16(const void* gp, void* lp) {
  __builtin_amdgcn_global_load_lds((const __attribute__((address_space(1))) void*)gp,
                                   (__attribute__((address_space(3))) void*)lp, 16, 0, 0);
}

// ---------------------------------------------------------------------------
// Kernel T: x [B,C,N] fp32 -> t [B,N,C] bf16   (B=32, C=640, N=1024)
// ---------------------------------------------------------------------------
__global__ __launch_bounds__(256) void k_transpose(const float* __restrict__ x,
                                                   bf16* __restrict__ t) {
  __shared__ float tile[64][65];
  const int b = blockIdx.z, c0 = blockIdx.y * 64, n0 = blockIdx.x * 64;
  const int tid = threadIdx.x, lx = tid & 63, ly = tid >> 6;
  const float* xp = x + ((size_t)b * 640 + c0) * 1024 + n0;
#pragma unroll
  for (int i = 0; i < 16; ++i) {
    int c = i * 4 + ly;
    tile[c][lx] = xp[(size_t)c * 1024 + lx];
  }
  __syncthreads();
  bf16* tp = t + ((size_t)b * 1024 + n0) * 640 + c0;
#pragma unroll
  for (int i = 0; i < 16; ++i) {
    int n = i * 4 + ly;
    tp[(size_t)n * 640 + lx] = (bf16)tile[lx][n];
  }
}

// ---------------------------------------------------------------------------
// Kernel Wc: cast one weight matrix [1024,640] fp32 -> bf16 (optionally scaled)
// ---------------------------------------------------------------------------
__global__ __launch_bounds__(256) void k_castw(const float* __restrict__ w,
                                               bf16* __restrict__ dst, float s) {
  int i = blockIdx.x * 256 + threadIdx.x;
  if (i < 655360) dst[i] = (bf16)(w[i] * s);
}

// ---------------------------------------------------------------------------
// Kernel P: C[32768 x 3072] = A[32768 x 640] * B[3072 x 640]^T  (bf16 in, bf16 out)
// 128x128 tile, BK=64, 4 waves (2x2), 16x16x32 MFMA, global_load_lds + XOR swizzle.
// Epilogue scatters into q/k/v [BH=512][N=1024][64] bf16.
// ---------------------------------------------------------------------------
__global__ __launch_bounds__(256) void k_gemm_qkv(const bf16* __restrict__ A,
                                                  const bf16* __restrict__ Bw,
                                                  bf16* __restrict__ qkv) {
  __shared__ __align__(16) bf16 As[128 * 64];
  __shared__ __align__(16) bf16 Bs[128 * 64];
  const int tid = threadIdx.x;
  const int lane = tid & 63;
  const int w = tid >> 6;
  const int wm = w & 1, wn = w >> 1;
  const int g = lane >> 4, ln = lane & 15;
  const int m0 = blockIdx.x * 128;
  const int n0 = blockIdx.y * 128;

  f32x4 acc[4][4];
#pragma unroll
  for (int i = 0; i < 4; ++i)
#pragma unroll
    for (int j = 0; j < 4; ++j)
#pragma unroll
      for (int r = 0; r < 4; ++r) acc[i][j][r] = 0.f;

  for (int k0 = 0; k0 < 640; k0 += 64) {
    // stage A and B tiles: 1024 16B-chunks each; chunk c holds global (m=c>>3, kq=(c&7)^(m&7))
#pragma unroll
    for (int it = 0; it < 4; ++it) {
      int c = it * 256 + w * 64 + lane;
      int m = c >> 3;
      int kq = (c & 7) ^ (m & 7);
      load_lds16(A + (size_t)(m0 + m) * 640 + (k0 + kq * 8), As + (size_t)(it * 256 + w * 64) * 8);
      load_lds16(Bw + (size_t)(n0 + m) * 640 + (k0 + kq * 8), Bs + (size_t)(it * 256 + w * 64) * 8);
    }
    __syncthreads();
#pragma unroll
    for (int kk = 0; kk < 2; ++kk) {
      bf16x8 af[4], bfr[4];
#pragma unroll
      for (int mi = 0; mi < 4; ++mi) {
        int m = wm * 64 + mi * 16 + ln;
        int cc = m * 8 + ((kk * 4 + g) ^ (m & 7));
        af[mi] = *(const bf16x8*)(As + cc * 8);
      }
#pragma unroll
      for (int ni = 0; ni < 4; ++ni) {
        int n = wn * 64 + ni * 16 + ln;
        int cc = n * 8 + ((kk * 4 + g) ^ (n & 7));
        bfr[ni] = *(const bf16x8*)(Bs + cc * 8);
      }
#pragma unroll
      for (int mi = 0; mi < 4; ++mi)
#pragma unroll
        for (int ni = 0; ni < 4; ++ni)
          acc[mi][ni] = __builtin_amdgcn_mfma_f32_16x16x32_bf16(af[mi], bfr[ni], acc[mi][ni], 0, 0, 0);
    }
    __syncthreads();
  }

  // epilogue: D layout col=lane&15, row=(lane>>4)*4+r  -> scatter to q/k/v [bh][n][d]
#pragma unroll
  for (int mi = 0; mi < 4; ++mi)
#pragma unroll
    for (int ni = 0; ni < 4; ++ni)
#pragma unroll
      for (int r = 0; r < 4; ++r) {
        int row = m0 + wm * 64 + mi * 16 + g * 4 + r;   // (b,n)
        int col = n0 + wn * 64 + ni * 16 + ln;          // (which,h,d)
        int bb = row >> 10, n = row & 1023;
        int which = col >> 10, h = (col >> 6) & 15, d = col & 63;
        qkv[(size_t)which * 33554432 +
            ((((size_t)bb * 16 + h) * 1024 + n) * 64 + d)] = (bf16)acc[mi][ni][r];
      }
}

// ---------------------------------------------------------------------------
// Kernel A: fused two-pass attention column-weights.
// grid 2048 1-D; decode so the 4 i-tiles of one bh land on the SAME XCD
// (idx % 8 equal) -> K re-reads hit that XCD's L2 (R4: FETCH 295->66 MB).
// Simple per-jt loads, NO explicit double-buffer: R4 showed prefetch pushes
// VGPR 84->132 and occupancy 31%->11%, a net loss. L2-hit latency (~250 cyc)
// is hidden by ~6 waves/SIMD of TLP instead.
// Pass 1: l_i = sum_j exp2(s_ij)  (q pre-scaled by scale*log2e)
// Pass 2: w_j += sum_i exp2(s_ij) / l_i   via atomicAdd.
// ---------------------------------------------------------------------------
__global__ __launch_bounds__(256) void k_attn(const bf16* __restrict__ q,
                                              const bf16* __restrict__ kmat,
                                              float* __restrict__ wsum) {
  const int idx = blockIdx.x;
  const int xcd = idx & 7;
  const int y = idx >> 3;
  const int it = y & 3;
  const int bh = xcd + ((y >> 2) << 3);   // 4 i-tiles of bh share idx%8
  const int tid = threadIdx.x;
  const int lane = tid & 63;
  const int w = tid >> 6;
  const int g = lane >> 4, ln = lane & 15;
  const bf16* qb = q + (size_t)bh * 65536;
  const bf16* kb = kmat + (size_t)bh * 65536;
  const int i0 = it * 256 + w * 64;

  const f32x4 zf = {0.f, 0.f, 0.f, 0.f};

  // Q fragments: A-layout m=lane&15, k=(lane>>4)*8+j ; held in regs for both passes
  bf16x8 qf[4][2];
#pragma unroll
  for (int mi = 0; mi < 4; ++mi)
#pragma unroll
    for (int kc = 0; kc < 2; ++kc)
      qf[mi][kc] = *(const bf16x8*)(qb + (size_t)(i0 + mi * 16 + ln) * 64 + kc * 32 + g * 8);

  float rs[4][4];
#pragma unroll
  for (int mi = 0; mi < 4; ++mi)
#pragma unroll
    for (int r = 0; r < 4; ++r) rs[mi][r] = 0.f;

  // ---- pass 1: row sums ----
  for (int jt = 0; jt < 16; ++jt) {
    bf16x8 kf[4][2];
#pragma unroll
    for (int ni = 0; ni < 4; ++ni)
#pragma unroll
      for (int kc = 0; kc < 2; ++kc)
        kf[ni][kc] = *(const bf16x8*)(kb + (size_t)(jt * 64 + ni * 16 + ln) * 64 + kc * 32 + g * 8);
#pragma unroll
    for (int mi = 0; mi < 4; ++mi)
#pragma unroll
      for (int ni = 0; ni < 4; ++ni) {
        f32x4 s = __builtin_amdgcn_mfma_f32_16x16x32_bf16(qf[mi][0], kf[ni][0], zf, 0, 0, 0);
        s = __builtin_amdgcn_mfma_f32_16x16x32_bf16(qf[mi][1], kf[ni][1], s, 0, 0, 0);
#pragma unroll
        for (int r = 0; r < 4; ++r) rs[mi][r] += EXP2(s[r]);
      }
  }
  // reduce row sums across the 16 lanes sharing g (cols live in lane&15)
  float rinv[4][4];
#pragma unroll
  for (int mi = 0; mi < 4; ++mi)
#pragma unroll
    for (int r = 0; r < 4; ++r) {
      float v = rs[mi][r];
      v += __shfl_xor(v, 1);
      v += __shfl_xor(v, 2);
      v += __shfl_xor(v, 4);
      v += __shfl_xor(v, 8);
      rinv[mi][r] = 1.0f / v;
    }

  // ---- pass 2: column sums scaled by 1/l_i ----
  for (int jt = 0; jt < 16; ++jt) {
    bf16x8 kf[4][2];
#pragma unroll
    for (int ni = 0; ni < 4; ++ni)
#pragma unroll
      for (int kc = 0; kc < 2; ++kc)
        kf[ni][kc] = *(const bf16x8*)(kb + (size_t)(jt * 64 + ni * 16 + ln) * 64 + kc * 32 + g * 8);
    float cs[4] = {0.f, 0.f, 0.f, 0.f};
#pragma unroll
    for (int mi = 0; mi < 4; ++mi)
#pragma unroll
      for (int ni = 0; ni < 4; ++ni) {
        f32x4 s = __builtin_amdgcn_mfma_f32_16x16x32_bf16(qf[mi][0], kf[ni][0], zf, 0, 0, 0);
        s = __builtin_amdgcn_mfma_f32_16x16x32_bf16(qf[mi][1], kf[ni][1], s, 0, 0, 0);
#pragma unroll
        for (int r = 0; r < 4; ++r) cs[ni] += EXP2(s[r]) * rinv[mi][r];
      }
#pragma unroll
    for (int ni = 0; ni < 4; ++ni) {
      float v = cs[ni];
      v += __shfl_xor(v, 16);
      v += __shfl_xor(v, 32);
      if (g == 0) atomicAdd(wsum + (size_t)bh * 1024 + jt * 64 + ni * 16 + ln, v);
    }
  }
}

// ---------------------------------------------------------------------------
// Kernel F: out[bh][d] = LN_d( (1/N) * sum_j w[bh][j] * V[bh][j][d] )
// ---------------------------------------------------------------------------
__global__ __launch_bounds__(256) void k_final(const float* __restrict__ wsum,
                                               const bf16* __restrict__ v,
                                               const float* __restrict__ gamma,
                                               const float* __restrict__ beta,
                                               float* __restrict__ out) {
  const int bh = blockIdx.x;
  const int tid = threadIdx.x;
  const int d = tid & 63, part = tid >> 6;
  const bf16* vb = v + (size_t)bh * 65536;
  const float* wb = wsum + (size_t)bh * 1024;
  float acc = 0.f;
  for (int j = part * 256; j < part * 256 + 256; ++j)
    acc += wb[j] * (float)vb[(size_t)j * 64 + d];
  __shared__ float red[4][64];
  red[part][d] = acc;
  __syncthreads();
  if (tid < 64) {
    float y = (red[0][d] + red[1][d] + red[2][d] + red[3][d]) * (1.0f / 1024.0f);
    float s1 = y;
#pragma unroll
    for (int off = 1; off < 64; off <<= 1) s1 += __shfl_xor(s1, off);
    float mu = s1 * (1.0f / 64.0f);
    float dy = y - mu;
    float s2 = dy * dy;
#pragma unroll
    for (int off = 1; off < 64; off <<= 1) s2 += __shfl_xor(s2, off);
    float rstd = rsqrtf(s2 * (1.0f / 64.0f) + 1e-5f);
    out[(size_t)bh * 64 + d] = dy * rstd * gamma[d] + beta[d];
  }
}

// ---------------------------------------------------------------------------
extern "C" void kernel_launch(void* const* d_in, const int* in_sizes, int n_in,
                              void* d_out, int out_size, void* d_ws, size_t ws_size,
                              hipStream_t stream) {
  const float* x     = (const float*)d_in[0];
  const float* Wq    = (const float*)d_in[1];
  const float* Wk    = (const float*)d_in[2];
  const float* Wv    = (const float*)d_in[3];
  const float* gamma = (const float*)d_in[4];
  const float* beta  = (const float*)d_in[5];
  float* out = (float*)d_out;

  char* ws = (char*)d_ws;
  bf16*  tbf  = (bf16*)ws;                    // 32768*640*2      = 41,943,040 B
  bf16*  wbf  = (bf16*)(ws + 41943040);       // 3072*640*2       =  3,932,160 B
  bf16*  qkv  = (bf16*)(ws + 45875200);       // 3*512*1024*64*2  = 201,326,592 B
  float* wsum = (float*)(ws + 247201792);     // 512*1024*4       =  2,097,152 B

  hipMemsetAsync(wsum, 0, (size_t)512 * 1024 * sizeof(float), stream);
  k_transpose<<<dim3(16, 10, 32), 256, 0, stream>>>(x, tbf);
  k_castw<<<2560, 256, 0, stream>>>(Wq, wbf, QSCALE);
  k_castw<<<2560, 256, 0, stream>>>(Wk, wbf + 655360, 1.0f);
  k_castw<<<2560, 256, 0, stream>>>(Wv, wbf + 1310720, 1.0f);
  k_gemm_qkv<<<dim3(256, 24), 256, 0, stream>>>(tbf, wbf, qkv);
  k_attn<<<2048, 256, 0, stream>>>(qkv, qkv + 33554432, wsum);
  k_final<<<512, 256, 0, stream>>>(wsum, qkv + 67108864, gamma, beta, out);
}

// Round 6
// 518.391 us; speedup vs baseline: 1.9552x; 1.0926x over previous
//
#include <hip/hip_runtime.h>
#include <hip/hip_bf16.h>

typedef __bf16 bf16;
typedef __bf16 bf16x8 __attribute__((ext_vector_type(8)));
typedef float f32x4 __attribute__((ext_vector_type(4)));

#define QSCALE 0.18033688011112042f  /* (1/8) * log2(e) : folds softmax scale into Wq */

// raw v_exp_f32 (exp2). Inputs here are |x| <~ 2.5 so no edge-case handling needed.
#define EXP2(x) __builtin_amdgcn_exp2f(x)

// ---- async global->LDS (16B per lane, wave-uniform LDS base + lane*16) ----
__device__ __forceinline__ void load_lds16(const void* gp, void* lp) {
  __builtin_amdgcn_global_load_lds((const __attribute__((address_space(1))) void*)gp,
                                   (__attribute__((address_space(3))) void*)lp, 16, 0, 0);
}

// ---------------------------------------------------------------------------
// Kernel T: x [B,C,N] fp32 -> t [B,N,C] bf16   (B=32, C=640, N=1024)
// ---------------------------------------------------------------------------
__global__ __launch_bounds__(256) void k_transpose(const float* __restrict__ x,
                                                   bf16* __restrict__ t) {
  __shared__ float tile[64][65];
  const int b = blockIdx.z, c0 = blockIdx.y * 64, n0 = blockIdx.x * 64;
  const int tid = threadIdx.x, lx = tid & 63, ly = tid >> 6;
  const float* xp = x + ((size_t)b * 640 + c0) * 1024 + n0;
#pragma unroll
  for (int i = 0; i < 16; ++i) {
    int c = i * 4 + ly;
    tile[c][lx] = xp[(size_t)c * 1024 + lx];
  }
  __syncthreads();
  bf16* tp = t + ((size_t)b * 1024 + n0) * 640 + c0;
#pragma unroll
  for (int i = 0; i < 16; ++i) {
    int n = i * 4 + ly;
    tp[(size_t)n * 640 + lx] = (bf16)tile[lx][n];
  }
}

// ---------------------------------------------------------------------------
// Kernel Wc: cast one weight matrix [1024,640] fp32 -> bf16 (optionally scaled)
// ---------------------------------------------------------------------------
__global__ __launch_bounds__(256) void k_castw(const float* __restrict__ w,
                                               bf16* __restrict__ dst, float s) {
  int i = blockIdx.x * 256 + threadIdx.x;
  if (i < 655360) dst[i] = (bf16)(w[i] * s);
}

// ---------------------------------------------------------------------------
// Kernel P: C[32768 x 3072] = A[32768 x 640] * B[3072 x 640]^T  (bf16 in, bf16 out)
// 128x128 tile, BK=64, 4 waves (2x2), 16x16x32 MFMA, global_load_lds + XOR swizzle.
// Epilogue scatters into q/k/v [BH=512][N=1024][64] bf16.
// ---------------------------------------------------------------------------
__global__ __launch_bounds__(256) void k_gemm_qkv(const bf16* __restrict__ A,
                                                  const bf16* __restrict__ Bw,
                                                  bf16* __restrict__ qkv) {
  __shared__ __align__(16) bf16 As[128 * 64];
  __shared__ __align__(16) bf16 Bs[128 * 64];
  const int tid = threadIdx.x;
  const int lane = tid & 63;
  const int w = tid >> 6;
  const int wm = w & 1, wn = w >> 1;
  const int g = lane >> 4, ln = lane & 15;
  const int m0 = blockIdx.x * 128;
  const int n0 = blockIdx.y * 128;

  f32x4 acc[4][4];
#pragma unroll
  for (int i = 0; i < 4; ++i)
#pragma unroll
    for (int j = 0; j < 4; ++j)
#pragma unroll
      for (int r = 0; r < 4; ++r) acc[i][j][r] = 0.f;

  for (int k0 = 0; k0 < 640; k0 += 64) {
    // stage A and B tiles: 1024 16B-chunks each; chunk c holds global (m=c>>3, kq=(c&7)^(m&7))
#pragma unroll
    for (int it = 0; it < 4; ++it) {
      int c = it * 256 + w * 64 + lane;
      int m = c >> 3;
      int kq = (c & 7) ^ (m & 7);
      load_lds16(A + (size_t)(m0 + m) * 640 + (k0 + kq * 8), As + (size_t)(it * 256 + w * 64) * 8);
      load_lds16(Bw + (size_t)(n0 + m) * 640 + (k0 + kq * 8), Bs + (size_t)(it * 256 + w * 64) * 8);
    }
    __syncthreads();
#pragma unroll
    for (int kk = 0; kk < 2; ++kk) {
      bf16x8 af[4], bfr[4];
#pragma unroll
      for (int mi = 0; mi < 4; ++mi) {
        int m = wm * 64 + mi * 16 + ln;
        int cc = m * 8 + ((kk * 4 + g) ^ (m & 7));
        af[mi] = *(const bf16x8*)(As + cc * 8);
      }
#pragma unroll
      for (int ni = 0; ni < 4; ++ni) {
        int n = wn * 64 + ni * 16 + ln;
        int cc = n * 8 + ((kk * 4 + g) ^ (n & 7));
        bfr[ni] = *(const bf16x8*)(Bs + cc * 8);
      }
#pragma unroll
      for (int mi = 0; mi < 4; ++mi)
#pragma unroll
        for (int ni = 0; ni < 4; ++ni)
          acc[mi][ni] = __builtin_amdgcn_mfma_f32_16x16x32_bf16(af[mi], bfr[ni], acc[mi][ni], 0, 0, 0);
    }
    __syncthreads();
  }

  // epilogue: D layout col=lane&15, row=(lane>>4)*4+r  -> scatter to q/k/v [bh][n][d]
#pragma unroll
  for (int mi = 0; mi < 4; ++mi)
#pragma unroll
    for (int ni = 0; ni < 4; ++ni)
#pragma unroll
      for (int r = 0; r < 4; ++r) {
        int row = m0 + wm * 64 + mi * 16 + g * 4 + r;   // (b,n)
        int col = n0 + wn * 64 + ni * 16 + ln;          // (which,h,d)
        int bb = row >> 10, n = row & 1023;
        int which = col >> 10, h = (col >> 6) & 15, d = col & 63;
        qkv[(size_t)which * 33554432 +
            ((((size_t)bb * 16 + h) * 1024 + n) * 64 + d)] = (bf16)acc[mi][ni][r];
      }
}

// ---------------------------------------------------------------------------
// Kernel A: fused two-pass attention column-weights.
// grid 2048 1-D with XCD swizzle (4 i-tiles of a bh share idx%8 -> K L2-hot;
// R5: FETCH 80 MB = unique footprint). K tiles staged block-level into LDS
// via global_load_lds (zero VGPR cost), 2 buffers, ONE barrier per tile:
//   sync (drains stage(jt), issued a full compute earlier -> cheap)
//   stage(jt+1) -> other buf   (safe: barrier proved compute(jt-1) done)
//   compute(jt) from cur buf   (overlaps with stage(jt+1) in flight)
// Chunks XOR-swizzled so ds_read_b128 fragments are 2-way-bank-free.
// Pass 1: l_i = sum_j exp2(s_ij)  (q pre-scaled by scale*log2e)
// Pass 2: w_j += sum_i exp2(s_ij) / l_i   via atomicAdd.
// ---------------------------------------------------------------------------
__global__ __launch_bounds__(256) void k_attn(const bf16* __restrict__ q,
                                              const bf16* __restrict__ kmat,
                                              float* __restrict__ wsum) {
  __shared__ __align__(16) bf16 Ks[2][4096];   // 2 x 64x64 bf16 = 16 KB
  const int idx = blockIdx.x;
  const int xcd = idx & 7;
  const int y = idx >> 3;
  const int it = y & 3;
  const int bh = xcd + ((y >> 2) << 3);   // 4 i-tiles of bh share idx%8
  const int tid = threadIdx.x;
  const int lane = tid & 63;
  const int w = tid >> 6;
  const int g = lane >> 4, ln = lane & 15;
  const bf16* qb = q + (size_t)bh * 65536;
  const bf16* kb = kmat + (size_t)bh * 65536;
  const int i0 = it * 256 + w * 64;

  const f32x4 zf = {0.f, 0.f, 0.f, 0.f};

  // stage K tile jt into Ks[buf]: 512 chunks of 16 B; chunk linear pos p
  // holds global (j = p>>3, kq = (p&7) ^ (j&7)). Per wave: 2 calls x 64 lanes.
#define STAGEK(buf, jt)                                                       \
  do {                                                                        \
    _Pragma("unroll") for (int call_ = 0; call_ < 2; ++call_) {               \
      int p_ = w * 128 + call_ * 64 + lane;                                   \
      int j_ = p_ >> 3;                                                       \
      int kq_ = (p_ & 7) ^ (j_ & 7);                                          \
      load_lds16(kb + (size_t)((jt) * 64 + j_) * 64 + kq_ * 8,                \
                 &Ks[buf][(size_t)(w * 128 + call_ * 64) * 8]);               \
    }                                                                         \
  } while (0)

  // read K frag (ni, kc) for this lane from Ks[buf]:
  // j = ni*16+ln, chunk c = (kc*4+g) ^ (j&7)
#define KFRAG(buf, ni, kc)                                                    \
  (*(const bf16x8*)(&Ks[buf][(size_t)(((ni) * 16 + ln) * 8 +                  \
                                      (((kc) * 4 + g) ^ (ln & 7))) * 8]))

  // Q fragments: A-layout m=lane&15, k=(lane>>4)*8+j ; held in regs for both passes
  bf16x8 qf[4][2];
#pragma unroll
  for (int mi = 0; mi < 4; ++mi)
#pragma unroll
    for (int kc = 0; kc < 2; ++kc)
      qf[mi][kc] = *(const bf16x8*)(qb + (size_t)(i0 + mi * 16 + ln) * 64 + kc * 32 + g * 8);

  float rs[4][4];
#pragma unroll
  for (int mi = 0; mi < 4; ++mi)
#pragma unroll
    for (int r = 0; r < 4; ++r) rs[mi][r] = 0.f;

  // ---- pass 1: row sums ----
  STAGEK(0, 0);
  for (int jt = 0; jt < 16; ++jt) {
    const int cur = jt & 1;
    __syncthreads();                      // drains stage(jt); syncs buffer handoff
    if (jt + 1 < 16) STAGEK(1 - cur, jt + 1);
    bf16x8 kf[4][2];
#pragma unroll
    for (int ni = 0; ni < 4; ++ni)
#pragma unroll
      for (int kc = 0; kc < 2; ++kc) kf[ni][kc] = KFRAG(cur, ni, kc);
#pragma unroll
    for (int mi = 0; mi < 4; ++mi)
#pragma unroll
      for (int ni = 0; ni < 4; ++ni) {
        f32x4 s = __builtin_amdgcn_mfma_f32_16x16x32_bf16(qf[mi][0], kf[ni][0], zf, 0, 0, 0);
        s = __builtin_amdgcn_mfma_f32_16x16x32_bf16(qf[mi][1], kf[ni][1], s, 0, 0, 0);
#pragma unroll
        for (int r = 0; r < 4; ++r) rs[mi][r] += EXP2(s[r]);
      }
  }
  // reduce row sums across the 16 lanes sharing g (cols live in lane&15)
  float rinv[4][4];
#pragma unroll
  for (int mi = 0; mi < 4; ++mi)
#pragma unroll
    for (int r = 0; r < 4; ++r) {
      float v = rs[mi][r];
      v += __shfl_xor(v, 1);
      v += __shfl_xor(v, 2);
      v += __shfl_xor(v, 4);
      v += __shfl_xor(v, 8);
      rinv[mi][r] = 1.0f / v;
    }

  // ---- pass 2: column sums scaled by 1/l_i ----
  // Safe to restage buf0: any wave still in pass-1 jt=15 reads buf1 only.
  STAGEK(0, 0);
  for (int jt = 0; jt < 16; ++jt) {
    const int cur = jt & 1;
    __syncthreads();
    if (jt + 1 < 16) STAGEK(1 - cur, jt + 1);
    bf16x8 kf[4][2];
#pragma unroll
    for (int ni = 0; ni < 4; ++ni)
#pragma unroll
      for (int kc = 0; kc < 2; ++kc) kf[ni][kc] = KFRAG(cur, ni, kc);
    float cs[4] = {0.f, 0.f, 0.f, 0.f};
#pragma unroll
    for (int mi = 0; mi < 4; ++mi)
#pragma unroll
      for (int ni = 0; ni < 4; ++ni) {
        f32x4 s = __builtin_amdgcn_mfma_f32_16x16x32_bf16(qf[mi][0], kf[ni][0], zf, 0, 0, 0);
        s = __builtin_amdgcn_mfma_f32_16x16x32_bf16(qf[mi][1], kf[ni][1], s, 0, 0, 0);
#pragma unroll
        for (int r = 0; r < 4; ++r) cs[ni] += EXP2(s[r]) * rinv[mi][r];
      }
#pragma unroll
    for (int ni = 0; ni < 4; ++ni) {
      float v = cs[ni];
      v += __shfl_xor(v, 16);
      v += __shfl_xor(v, 32);
      if (g == 0) atomicAdd(wsum + (size_t)bh * 1024 + jt * 64 + ni * 16 + ln, v);
    }
  }
#undef STAGEK
#undef KFRAG
}

// ---------------------------------------------------------------------------
// Kernel F: out[bh][d] = LN_d( (1/N) * sum_j w[bh][j] * V[bh][j][d] )
// ---------------------------------------------------------------------------
__global__ __launch_bounds__(256) void k_final(const float* __restrict__ wsum,
                                               const bf16* __restrict__ v,
                                               const float* __restrict__ gamma,
                                               const float* __restrict__ beta,
                                               float* __restrict__ out) {
  const int bh = blockIdx.x;
  const int tid = threadIdx.x;
  const int d = tid & 63, part = tid >> 6;
  const bf16* vb = v + (size_t)bh * 65536;
  const float* wb = wsum + (size_t)bh * 1024;
  float acc = 0.f;
  for (int j = part * 256; j < part * 256 + 256; ++j)
    acc += wb[j] * (float)vb[(size_t)j * 64 + d];
  __shared__ float red[4][64];
  red[part][d] = acc;
  __syncthreads();
  if (tid < 64) {
    float y = (red[0][d] + red[1][d] + red[2][d] + red[3][d]) * (1.0f / 1024.0f);
    float s1 = y;
#pragma unroll
    for (int off = 1; off < 64; off <<= 1) s1 += __shfl_xor(s1, off);
    float mu = s1 * (1.0f / 64.0f);
    float dy = y - mu;
    float s2 = dy * dy;
#pragma unroll
    for (int off = 1; off < 64; off <<= 1) s2 += __shfl_xor(s2, off);
    float rstd = rsqrtf(s2 * (1.0f / 64.0f) + 1e-5f);
    out[(size_t)bh * 64 + d] = dy * rstd * gamma[d] + beta[d];
  }
}

// ---------------------------------------------------------------------------
extern "C" void kernel_launch(void* const* d_in, const int* in_sizes, int n_in,
                              void* d_out, int out_size, void* d_ws, size_t ws_size,
                              hipStream_t stream) {
  const float* x     = (const float*)d_in[0];
  const float* Wq    = (const float*)d_in[1];
  const float* Wk    = (const float*)d_in[2];
  const float* Wv    = (const float*)d_in[3];
  const float* gamma = (const float*)d_in[4];
  const float* beta  = (const float*)d_in[5];
  float* out = (float*)d_out;

  char* ws = (char*)d_ws;
  bf16*  tbf  = (bf16*)ws;                    // 32768*640*2      = 41,943,040 B
  bf16*  wbf  = (bf16*)(ws + 41943040);       // 3072*640*2       =  3,932,160 B
  bf16*  qkv  = (bf16*)(ws + 45875200);       // 3*512*1024*64*2  = 201,326,592 B
  float* wsum = (float*)(ws + 247201792);     // 512*1024*4       =  2,097,152 B

  hipMemsetAsync(wsum, 0, (size_t)512 * 1024 * sizeof(float), stream);
  k_transpose<<<dim3(16, 10, 32), 256, 0, stream>>>(x, tbf);
  k_castw<<<2560, 256, 0, stream>>>(Wq, wbf, QSCALE);
  k_castw<<<2560, 256, 0, stream>>>(Wk, wbf + 655360, 1.0f);
  k_castw<<<2560, 256, 0, stream>>>(Wv, wbf + 1310720, 1.0f);
  k_gemm_qkv<<<dim3(256, 24), 256, 0, stream>>>(tbf, wbf, qkv);
  k_attn<<<2048, 256, 0, stream>>>(qkv, qkv + 33554432, wsum);
  k_final<<<512, 256, 0, stream>>>(wsum, qkv + 67108864, gamma, beta, out);
}

// Round 7
// 513.121 us; speedup vs baseline: 1.9752x; 1.0103x over previous
//
#include <hip/hip_runtime.h>
#include <hip/hip_bf16.h>

typedef __bf16 bf16;
typedef __bf16 bf16x8 __attribute__((ext_vector_type(8)));
typedef float f32x4 __attribute__((ext_vector_type(4)));

#define QSCALE 0.18033688011112042f  /* (1/8) * log2(e) : folds softmax scale into Wq */

// raw v_exp_f32 (exp2). Inputs here are |x| <~ 2.5 so no edge-case handling needed.
#define EXP2(x) __builtin_amdgcn_exp2f(x)

// ---- async global->LDS (16B per lane, wave-uniform LDS base + lane*16) ----
__device__ __forceinline__ void load_lds16(const void* gp, void* lp) {
  __builtin_amdgcn_global_load_lds((const __attribute__((address_space(1))) void*)gp,
                                   (__attribute__((address_space(3))) void*)lp, 16, 0, 0);
}

// ---------------------------------------------------------------------------
// Kernel T: x [B,C,N] fp32 -> t [B,N,C] bf16   (B=32, C=640, N=1024)
// ---------------------------------------------------------------------------
__global__ __launch_bounds__(256) void k_transpose(const float* __restrict__ x,
                                                   bf16* __restrict__ t) {
  __shared__ float tile[64][65];
  const int b = blockIdx.z, c0 = blockIdx.y * 64, n0 = blockIdx.x * 64;
  const int tid = threadIdx.x, lx = tid & 63, ly = tid >> 6;
  const float* xp = x + ((size_t)b * 640 + c0) * 1024 + n0;
#pragma unroll
  for (int i = 0; i < 16; ++i) {
    int c = i * 4 + ly;
    tile[c][lx] = xp[(size_t)c * 1024 + lx];
  }
  __syncthreads();
  bf16* tp = t + ((size_t)b * 1024 + n0) * 640 + c0;
#pragma unroll
  for (int i = 0; i < 16; ++i) {
    int n = i * 4 + ly;
    tp[(size_t)n * 640 + lx] = (bf16)tile[lx][n];
  }
}

// ---------------------------------------------------------------------------
// Kernel Wc: cast all three weight matrices fp32 -> bf16 (Wq pre-scaled)
// ---------------------------------------------------------------------------
__global__ __launch_bounds__(256) void k_castw3(const float* __restrict__ wq,
                                                const float* __restrict__ wk,
                                                const float* __restrict__ wv,
                                                bf16* __restrict__ dst) {
  int i = blockIdx.x * 256 + threadIdx.x;
  if (i < 655360) dst[i] = (bf16)(wq[i] * QSCALE);
  else if (i < 1310720) dst[i] = (bf16)wk[i - 655360];
  else if (i < 1966080) dst[i] = (bf16)wv[i - 1310720];
}

// ---------------------------------------------------------------------------
// Kernel P: C[32768 x 3072] = A[32768 x 640] * B[3072 x 640]^T  (bf16 in/out)
// 128x128 tile, BK=64, 4 waves (2x2), 16x16x32 MFMA.
// R7: single-barrier async double-buffer (R6-proven shape): barrier drains
// stage(kt) issued one full compute earlier -> cheap; stage(kt+1) overlaps
// compute(kt). Epilogue transposes through LDS -> bf16x8 (16 B) stores.
// ---------------------------------------------------------------------------
__global__ __launch_bounds__(256) void k_gemm_qkv(const bf16* __restrict__ A,
                                                  const bf16* __restrict__ Bw,
                                                  bf16* __restrict__ qkv) {
  __shared__ __align__(16) bf16 smem[2][2][8192];   // [buf][A/B][128*64] = 64 KB
  const int tid = threadIdx.x;
  const int lane = tid & 63;
  const int w = tid >> 6;
  const int wm = w & 1, wn = w >> 1;
  const int g = lane >> 4, ln = lane & 15;
  const int m0 = blockIdx.x * 128;
  const int n0 = blockIdx.y * 128;

  f32x4 acc[4][4];
#pragma unroll
  for (int i = 0; i < 4; ++i)
#pragma unroll
    for (int j = 0; j < 4; ++j)
#pragma unroll
      for (int r = 0; r < 4; ++r) acc[i][j][r] = 0.f;

  // stage A+B K-tile kt into smem[buf]: chunk c holds (m=c>>3, kq=(c&7)^(m&7))
#define GSTAGE(buf, kt)                                                        \
  do {                                                                         \
    _Pragma("unroll") for (int it_ = 0; it_ < 4; ++it_) {                      \
      int c_ = it_ * 256 + w * 64 + lane;                                      \
      int m_ = c_ >> 3;                                                        \
      int kq_ = (c_ & 7) ^ (m_ & 7);                                           \
      load_lds16(A + (size_t)(m0 + m_) * 640 + ((kt) * 64 + kq_ * 8),          \
                 &smem[buf][0][(size_t)(it_ * 256 + w * 64) * 8]);             \
      load_lds16(Bw + (size_t)(n0 + m_) * 640 + ((kt) * 64 + kq_ * 8),        \
                 &smem[buf][1][(size_t)(it_ * 256 + w * 64) * 8]);             \
    }                                                                          \
  } while (0)

  GSTAGE(0, 0);
  for (int kt = 0; kt < 10; ++kt) {
    const int cur = kt & 1;
    __syncthreads();                    // drains stage(kt); buffer handoff
    if (kt + 1 < 10) GSTAGE(1 - cur, kt + 1);
    const bf16* As = smem[cur][0];
    const bf16* Bs = smem[cur][1];
#pragma unroll
    for (int kk = 0; kk < 2; ++kk) {
      bf16x8 af[4], bfr[4];
#pragma unroll
      for (int mi = 0; mi < 4; ++mi) {
        int m = wm * 64 + mi * 16 + ln;
        int cc = m * 8 + ((kk * 4 + g) ^ (m & 7));
        af[mi] = *(const bf16x8*)(As + cc * 8);
      }
#pragma unroll
      for (int ni = 0; ni < 4; ++ni) {
        int n = wn * 64 + ni * 16 + ln;
        int cc = n * 8 + ((kk * 4 + g) ^ (n & 7));
        bfr[ni] = *(const bf16x8*)(Bs + cc * 8);
      }
#pragma unroll
      for (int mi = 0; mi < 4; ++mi)
#pragma unroll
        for (int ni = 0; ni < 4; ++ni)
          acc[mi][ni] = __builtin_amdgcn_mfma_f32_16x16x32_bf16(af[mi], bfr[ni], acc[mi][ni], 0, 0, 0);
    }
  }
#undef GSTAGE

  // ---- epilogue: transpose through LDS, then 16 B stores ----
  __syncthreads();                       // all compute done; smem reusable
  bf16* ct = &smem[0][0][0];             // 32768 bf16 avail; stride 136 (pad)
#pragma unroll
  for (int mi = 0; mi < 4; ++mi)
#pragma unroll
    for (int ni = 0; ni < 4; ++ni)
#pragma unroll
      for (int r = 0; r < 4; ++r) {
        int row = wm * 64 + mi * 16 + g * 4 + r;
        int col = wn * 64 + ni * 16 + ln;
        ct[row * 136 + col] = (bf16)acc[mi][ni][r];
      }
  __syncthreads();
  const int which = n0 >> 10;
  const int hbase = (n0 >> 6) & 15;
#pragma unroll
  for (int p = 0; p < 8; ++p) {
    int row = p * 16 + (tid >> 4);       // tile row 0..127
    int chunk = tid & 15;                // 16 chunks of 8 cols
    bf16x8 vv = *(const bf16x8*)(ct + row * 136 + chunk * 8);
    int gr = m0 + row;
    int bb = gr >> 10, n = gr & 1023;
    int h = hbase + (chunk >> 3);
    int d0 = (chunk & 7) * 8;
    *(bf16x8*)(qkv + (size_t)which * 33554432 +
               (((size_t)bb * 16 + h) * 1024 + n) * 64 + d0) = vv;
  }
}

// ---------------------------------------------------------------------------
// Kernel A: fused two-pass attention column-weights.
// grid 2048 1-D with XCD swizzle (4 i-tiles of a bh share idx%8 -> K L2-hot;
// R5: FETCH 80 MB = unique footprint). K tiles staged block-level into LDS
// via global_load_lds (zero VGPR cost), 2 buffers, ONE barrier per tile.
// Pass 1: l_i = sum_j exp2(s_ij)  (q pre-scaled by scale*log2e)
// Pass 2: w_j += sum_i exp2(s_ij) / l_i   via atomicAdd.
// ---------------------------------------------------------------------------
__global__ __launch_bounds__(256) void k_attn(const bf16* __restrict__ q,
                                              const bf16* __restrict__ kmat,
                                              float* __restrict__ wsum) {
  __shared__ __align__(16) bf16 Ks[2][4096];   // 2 x 64x64 bf16 = 16 KB
  const int idx = blockIdx.x;
  const int xcd = idx & 7;
  const int y = idx >> 3;
  const int it = y & 3;
  const int bh = xcd + ((y >> 2) << 3);   // 4 i-tiles of bh share idx%8
  const int tid = threadIdx.x;
  const int lane = tid & 63;
  const int w = tid >> 6;
  const int g = lane >> 4, ln = lane & 15;
  const bf16* qb = q + (size_t)bh * 65536;
  const bf16* kb = kmat + (size_t)bh * 65536;
  const int i0 = it * 256 + w * 64;

  const f32x4 zf = {0.f, 0.f, 0.f, 0.f};

#define STAGEK(buf, jt)                                                       \
  do {                                                                        \
    _Pragma("unroll") for (int call_ = 0; call_ < 2; ++call_) {               \
      int p_ = w * 128 + call_ * 64 + lane;                                   \
      int j_ = p_ >> 3;                                                       \
      int kq_ = (p_ & 7) ^ (j_ & 7);                                          \
      load_lds16(kb + (size_t)((jt) * 64 + j_) * 64 + kq_ * 8,                \
                 &Ks[buf][(size_t)(w * 128 + call_ * 64) * 8]);               \
    }                                                                         \
  } while (0)

#define KFRAG(buf, ni, kc)                                                    \
  (*(const bf16x8*)(&Ks[buf][(size_t)(((ni) * 16 + ln) * 8 +                  \
                                      (((kc) * 4 + g) ^ (ln & 7))) * 8]))

  // Q fragments: A-layout m=lane&15, k=(lane>>4)*8+j ; held in regs for both passes
  bf16x8 qf[4][2];
#pragma unroll
  for (int mi = 0; mi < 4; ++mi)
#pragma unroll
    for (int kc = 0; kc < 2; ++kc)
      qf[mi][kc] = *(const bf16x8*)(qb + (size_t)(i0 + mi * 16 + ln) * 64 + kc * 32 + g * 8);

  float rs[4][4];
#pragma unroll
  for (int mi = 0; mi < 4; ++mi)
#pragma unroll
    for (int r = 0; r < 4; ++r) rs[mi][r] = 0.f;

  // ---- pass 1: row sums ----
  STAGEK(0, 0);
  for (int jt = 0; jt < 16; ++jt) {
    const int cur = jt & 1;
    __syncthreads();                      // drains stage(jt); buffer handoff
    if (jt + 1 < 16) STAGEK(1 - cur, jt + 1);
    bf16x8 kf[4][2];
#pragma unroll
    for (int ni = 0; ni < 4; ++ni)
#pragma unroll
      for (int kc = 0; kc < 2; ++kc) kf[ni][kc] = KFRAG(cur, ni, kc);
#pragma unroll
    for (int mi = 0; mi < 4; ++mi)
#pragma unroll
      for (int ni = 0; ni < 4; ++ni) {
        f32x4 s = __builtin_amdgcn_mfma_f32_16x16x32_bf16(qf[mi][0], kf[ni][0], zf, 0, 0, 0);
        s = __builtin_amdgcn_mfma_f32_16x16x32_bf16(qf[mi][1], kf[ni][1], s, 0, 0, 0);
#pragma unroll
        for (int r = 0; r < 4; ++r) rs[mi][r] += EXP2(s[r]);
      }
  }
  // reduce row sums across the 16 lanes sharing g (cols live in lane&15)
  float rinv[4][4];
#pragma unroll
  for (int mi = 0; mi < 4; ++mi)
#pragma unroll
    for (int r = 0; r < 4; ++r) {
      float v = rs[mi][r];
      v += __shfl_xor(v, 1);
      v += __shfl_xor(v, 2);
      v += __shfl_xor(v, 4);
      v += __shfl_xor(v, 8);
      rinv[mi][r] = 1.0f / v;
    }

  // ---- pass 2: column sums scaled by 1/l_i ----
  STAGEK(0, 0);
  for (int jt = 0; jt < 16; ++jt) {
    const int cur = jt & 1;
    __syncthreads();
    if (jt + 1 < 16) STAGEK(1 - cur, jt + 1);
    bf16x8 kf[4][2];
#pragma unroll
    for (int ni = 0; ni < 4; ++ni)
#pragma unroll
      for (int kc = 0; kc < 2; ++kc) kf[ni][kc] = KFRAG(cur, ni, kc);
    float cs[4] = {0.f, 0.f, 0.f, 0.f};
#pragma unroll
    for (int mi = 0; mi < 4; ++mi)
#pragma unroll
      for (int ni = 0; ni < 4; ++ni) {
        f32x4 s = __builtin_amdgcn_mfma_f32_16x16x32_bf16(qf[mi][0], kf[ni][0], zf, 0, 0, 0);
        s = __builtin_amdgcn_mfma_f32_16x16x32_bf16(qf[mi][1], kf[ni][1], s, 0, 0, 0);
#pragma unroll
        for (int r = 0; r < 4; ++r) cs[ni] += EXP2(s[r]) * rinv[mi][r];
      }
#pragma unroll
    for (int ni = 0; ni < 4; ++ni) {
      float v = cs[ni];
      v += __shfl_xor(v, 16);
      v += __shfl_xor(v, 32);
      if (g == 0) atomicAdd(wsum + (size_t)bh * 1024 + jt * 64 + ni * 16 + ln, v);
    }
  }
#undef STAGEK
#undef KFRAG
}

// ---------------------------------------------------------------------------
// Kernel F: out[bh][d] = LN_d( (1/N) * sum_j w[bh][j] * V[bh][j][d] )
// ---------------------------------------------------------------------------
__global__ __launch_bounds__(256) void k_final(const float* __restrict__ wsum,
                                               const bf16* __restrict__ v,
                                               const float* __restrict__ gamma,
                                               const float* __restrict__ beta,
                                               float* __restrict__ out) {
  const int bh = blockIdx.x;
  const int tid = threadIdx.x;
  const int d = tid & 63, part = tid >> 6;
  const bf16* vb = v + (size_t)bh * 65536;
  const float* wb = wsum + (size_t)bh * 1024;
  float acc = 0.f;
  for (int j = part * 256; j < part * 256 + 256; ++j)
    acc += wb[j] * (float)vb[(size_t)j * 64 + d];
  __shared__ float red[4][64];
  red[part][d] = acc;
  __syncthreads();
  if (tid < 64) {
    float y = (red[0][d] + red[1][d] + red[2][d] + red[3][d]) * (1.0f / 1024.0f);
    float s1 = y;
#pragma unroll
    for (int off = 1; off < 64; off <<= 1) s1 += __shfl_xor(s1, off);
    float mu = s1 * (1.0f / 64.0f);
    float dy = y - mu;
    float s2 = dy * dy;
#pragma unroll
    for (int off = 1; off < 64; off <<= 1) s2 += __shfl_xor(s2, off);
    float rstd = rsqrtf(s2 * (1.0f / 64.0f) + 1e-5f);
    out[(size_t)bh * 64 + d] = dy * rstd * gamma[d] + beta[d];
  }
}

// ---------------------------------------------------------------------------
extern "C" void kernel_launch(void* const* d_in, const int* in_sizes, int n_in,
                              void* d_out, int out_size, void* d_ws, size_t ws_size,
                              hipStream_t stream) {
  const float* x     = (const float*)d_in[0];
  const float* Wq    = (const float*)d_in[1];
  const float* Wk    = (const float*)d_in[2];
  const float* Wv    = (const float*)d_in[3];
  const float* gamma = (const float*)d_in[4];
  const float* beta  = (const float*)d_in[5];
  float* out = (float*)d_out;

  char* ws = (char*)d_ws;
  bf16*  tbf  = (bf16*)ws;                    // 32768*640*2      = 41,943,040 B
  bf16*  wbf  = (bf16*)(ws + 41943040);       // 3072*640*2       =  3,932,160 B
  bf16*  qkv  = (bf16*)(ws + 45875200);       // 3*512*1024*64*2  = 201,326,592 B
  float* wsum = (float*)(ws + 247201792);     // 512*1024*4       =  2,097,152 B

  hipMemsetAsync(wsum, 0, (size_t)512 * 1024 * sizeof(float), stream);
  k_transpose<<<dim3(16, 10, 32), 256, 0, stream>>>(x, tbf);
  k_castw3<<<7680, 256, 0, stream>>>(Wq, Wk, Wv, wbf);
  k_gemm_qkv<<<dim3(256, 24), 256, 0, stream>>>(tbf, wbf, qkv);
  k_attn<<<2048, 256, 0, stream>>>(qkv, qkv + 33554432, wsum);
  k_final<<<512, 256, 0, stream>>>(wsum, qkv + 67108864, gamma, beta, out);
}